// Round 8
// baseline (178.717 us; speedup 1.0000x reference)
//
#include <hip/hip_runtime.h>

#define BATCH 4
#define CH    256
#define NPIX  4096
#define CQD   32

typedef __bf16 bf16;
typedef bf16 bf16x8 __attribute__((ext_vector_type(8)));
typedef bf16 bf16x4 __attribute__((ext_vector_type(4)));
typedef float f32x4 __attribute__((ext_vector_type(4)));

#define MFMA16 __builtin_amdgcn_mfma_f32_16x16x32_bf16

#define GLOAD_LDS16(g, l) __builtin_amdgcn_global_load_lds( \
    (const __attribute__((address_space(1))) void*)(g),     \
    (__attribute__((address_space(3))) void*)(l), 16, 0, 0)

// ---------------------------------------------------------------------------
// Kernel 0: pack weights to bf16, stacked [320][256]:
// rows 0-31 = Wq/64 (q-scale folded), 32-63 = Wk, 64-319 = Wv. Bias likewise.
// ---------------------------------------------------------------------------
__global__ __launch_bounds__(256) void prep_kernel(
    const float* __restrict__ Wq, const float* __restrict__ bq,
    const float* __restrict__ Wk, const float* __restrict__ bk,
    const float* __restrict__ Wv, const float* __restrict__ bv,
    bf16* __restrict__ Wb, float* __restrict__ bb)
{
    int r = blockIdx.x, c = threadIdx.x;
    const float* W; const float* bs; float sc; int rr;
    if (r < 32)      { W = Wq; bs = bq; sc = 0.015625f; rr = r; }
    else if (r < 64) { W = Wk; bs = bk; sc = 1.0f;      rr = r - 32; }
    else             { W = Wv; bs = bv; sc = 1.0f;      rr = r - 64; }
    Wb[(size_t)r * CH + c] = (bf16)(W[(size_t)rr * CH + c] * sc);
    if (c == 0) bb[r] = bs[rr] * sc;
}

// ---------------------------------------------------------------------------
// Kernel 1: fused 1x1-conv projections via MFMA (unchanged from R6).
// ---------------------------------------------------------------------------
__global__ __launch_bounds__(256) void proj_kernel(
    const float* __restrict__ x,
    const bf16* __restrict__ Wb, const float* __restrict__ bb,
    bf16* __restrict__ qp, bf16* __restrict__ kp, bf16* __restrict__ vT)
{
    __shared__ __align__(16) bf16 xT[32][264];       // 16.9 KB [n_local][c]
    __shared__ __align__(16) bf16 vstage[4][16][40]; // 5 KB per-wave bounce

    const int t  = threadIdx.x;
    const int b  = blockIdx.x >> 7;
    const int n0 = (blockIdx.x & 127) << 5;
    const int w    = t >> 6;
    const int lane = t & 63;
    const int l16  = t & 15;
    const int quad = (t & 63) >> 4;

    const float* xb = x + (size_t)b * CH * NPIX;
#pragma unroll
    for (int j = 0; j < 8; ++j) {
        int id = t + j * 256;
        int c  = id >> 3;
        int n4 = (id & 7) << 2;
        float4 vv = *(const float4*)(xb + (size_t)c * NPIX + n0 + n4);
        xT[n4 + 0][c] = (bf16)vv.x;
        xT[n4 + 1][c] = (bf16)vv.y;
        xT[n4 + 2][c] = (bf16)vv.z;
        xT[n4 + 3][c] = (bf16)vv.w;
    }
    __syncthreads();

    for (int rt = 0; rt < 5; ++rt) {
        int ro = w * 80 + rt * 16;
        int kind = (ro < 32) ? 0 : (ro < 64) ? 1 : 2;

        bf16x8 afrag[8];
        const bf16* wrow = Wb + (size_t)(ro + l16) * CH + quad * 8;
#pragma unroll
        for (int kc = 0; kc < 8; ++kc)
            afrag[kc] = *(const bf16x8*)(wrow + kc * 32);
        float bv4[4];
#pragma unroll
        for (int r = 0; r < 4; ++r) bv4[r] = bb[ro + quad * 4 + r];

#pragma unroll
        for (int nt = 0; nt < 2; ++nt) {
            f32x4 acc = {0.f, 0.f, 0.f, 0.f};
#pragma unroll
            for (int kc = 0; kc < 8; ++kc) {
                bf16x8 bfr = *(const bf16x8*)&xT[nt * 16 + l16][kc * 32 + quad * 8];
                acc = MFMA16(afrag[kc], bfr, acc, 0, 0, 0);
            }
            if (kind != 2) {
                bf16x4 pk;
#pragma unroll
                for (int r = 0; r < 4; ++r)
                    pk[r] = (bf16)(acc[r] + bv4[r]);
                int n = n0 + nt * 16 + l16;
                int col = (kind == 0 ? ro : ro - 32) + quad * 4;
                bf16* dst = (kind == 0) ? qp : kp;
                *(bf16x4*)&dst[((size_t)b * NPIX + n) * CQD + col] = pk;
            } else {
#pragma unroll
                for (int r = 0; r < 4; ++r)
                    vstage[w][quad * 4 + r][nt * 16 + l16] = (bf16)(acc[r] + bv4[r]);
            }
        }
        if (kind == 2) {
            int vrow = lane >> 2, vcc = lane & 3;
            bf16x8 chunk = *(const bf16x8*)&vstage[w][vrow][vcc * 8];
            *(bf16x8*)&vT[((size_t)b * CH + (ro - 64) + vrow) * NPIX + n0 + vcc * 8] = chunk;
        }
    }
}

// ---------------------------------------------------------------------------
// Kernel 2: split-K flash attention, channel-split (R7 structure, R8 fix).
// Wave = (qg = w>>1) x (cg = w&1): 32 q-rows x 128 channels -> o = 64 AGPRs.
// 32-key tiles: Vt dbuf [2][256][32] = 32 KB + Pb 8 KB = 40 KB LDS.
// Async single-barrier K-loop (Vt via global_load_lds one iter ahead, K in
// registers, m=0 softmax, source-side XOR swizzle).
// FIX(R8): Opart bounce-out is 16 rows x 128 cols = 256 chunks -> FOUR
// 64-lane x 16B passes (vrow=lane>>4, vcc=lane&15). R7 used 2 passes with
// vcc=lane&7, leaving channel cols 64..127 of each half poisoned.
// ---------------------------------------------------------------------------
template<int S, bool DIRECT>
__global__ __launch_bounds__(256, 3) void attn_kernel(
    const bf16* __restrict__ qp, const bf16* __restrict__ kp,
    const bf16* __restrict__ vT,
    bf16* __restrict__ Opart, float* __restrict__ Lpart,
    float* __restrict__ out)
{
    __shared__ __align__(16) bf16 Vt[2][256][32];    // 32 KB
    __shared__ __align__(16) bf16 Pb[4][2][16][32];  // 8 KB, wave-private

    const int t    = threadIdx.x;
    const int bid  = blockIdx.x;
    const int s    = bid % S;
    const int tq   = bid / S;
    const int b    = tq >> 6;
    const int qt   = tq & 63;
    const int n0   = qt << 6;
    const int w    = t >> 6;
    const int qg   = w >> 1;    // q-row group (32 rows)
    const int cg   = w & 1;     // channel half (128 ch)
    const int lane = t & 63;
    const int l16  = t & 15;
    const int quad = (t & 63) >> 4;
    const int sw   = l16 & 3;   // 4-chunk swizzle key

    const bf16* qpb = qp + ((size_t)b * NPIX + n0 + qg * 32) * CQD;
    bf16x8 qfrag[2];
    qfrag[0] = *(const bf16x8*)(qpb + (size_t)l16 * CQD + quad * 8);
    qfrag[1] = *(const bf16x8*)(qpb + (size_t)(16 + l16) * CQD + quad * 8);

    f32x4 o[2][8];
#pragma unroll
    for (int g = 0; g < 2; ++g)
#pragma unroll
        for (int ct = 0; ct < 8; ++ct) o[g][ct] = (f32x4){0.f, 0.f, 0.f, 0.f};
    float lsum[2] = {0.f, 0.f};

    const bf16* kpb = kp + (size_t)b * NPIX * CQD;
    const bf16* vTb = vT + (size_t)b * CH * NPIX;
    const int k0 = s * (NPIX / S);
    const int iters = NPIX / S / 32;

    const int vrow_off = lane >> 2;
    const int vchunk   = (lane & 3) ^ (vrow_off & 3);
    auto issue_vt = [&](int buf, int m0) {
#pragma unroll
        for (int j = 0; j < 4; ++j) {
            int rowbase = w * 64 + j * 16;
            const bf16* src = vTb + (size_t)(rowbase + vrow_off) * NPIX + m0 + vchunk * 8;
            GLOAD_LDS16(src, &Vt[buf][rowbase][0]);
        }
    };
    auto load_kf = [&](int m0, bf16x8* kf) {
#pragma unroll
        for (int mt = 0; mt < 2; ++mt)
            kf[mt] = *(const bf16x8*)(kpb + (size_t)(m0 + mt * 16 + l16) * CQD + quad * 8);
    };

    bf16x8 kfa[2], kfb[2];
    issue_vt(0, k0);
    load_kf(k0, kfa);
    __syncthreads();

    for (int mi = 0; mi < iters; ++mi) {
        const int cur = mi & 1;
        if (mi + 1 < iters) {
            issue_vt(cur ^ 1, k0 + ((mi + 1) << 5));
            load_kf(k0 + ((mi + 1) << 5), kfb);
        }

        // S^T = K Q^T : D[key=mt*16+quad*4+r][q=l16]
        f32x4 sv[2][2];
#pragma unroll
        for (int mt = 0; mt < 2; ++mt) {
            f32x4 z = {0.f, 0.f, 0.f, 0.f};
            sv[0][mt] = MFMA16(kfa[mt], qfrag[0], z, 0, 0, 0);
            sv[1][mt] = MFMA16(kfa[mt], qfrag[1], z, 0, 0, 0);
        }

        // p = exp(s) (m=0); Pb[q=l16][32 keys], chunk c at slot c^sw
        bf16x8 pf[2];
#pragma unroll
        for (int g = 0; g < 2; ++g) {
            float rs = 0.f;
#pragma unroll
            for (int mt = 0; mt < 2; ++mt) {
                bf16x4 pk;
#pragma unroll
                for (int r = 0; r < 4; ++r) {
                    float e = __expf(sv[g][mt][r]);
                    rs += e;
                    pk[r] = (bf16)e;
                }
                int slot = (2 * mt + (quad >> 1)) ^ sw;
                *(bf16x4*)&Pb[w][g][l16][slot * 8 + (quad & 1) * 4] = pk;
            }
            lsum[g] += rs;
        }
#pragma unroll
        for (int g = 0; g < 2; ++g)
            pf[g] = *(const bf16x8*)&Pb[w][g][l16][(quad ^ sw) * 8];

        // PV over this wave's 128-ch half; row&3 == sw
#pragma unroll
        for (int ct = 0; ct < 8; ++ct) {
            int row = cg * 128 + ct * 16 + l16;
            bf16x8 v = *(const bf16x8*)&Vt[cur][row][(quad ^ sw) * 8];
            o[0][ct] = MFMA16(pf[0], v, o[0][ct], 0, 0, 0);
            o[1][ct] = MFMA16(pf[1], v, o[1][ct], 0, 0, 0);
        }
        __syncthreads();   // drains prefetch vmcnt + orders buffer swap
#pragma unroll
        for (int i = 0; i < 2; ++i) kfa[i] = kfb[i];
    }

    float l_g[2];
#pragma unroll
    for (int g = 0; g < 2; ++g) {
        float v = lsum[g];
        v += __shfl_xor(v, 16);
        v += __shfl_xor(v, 32);
        l_g[g] = v;
    }

    if (!DIRECT) {
        const size_t prb = ((size_t)s * BATCH + b) * NPIX + n0 + qg * 32;
        if (cg == 0 && quad == 0) {
#pragma unroll
            for (int g = 0; g < 2; ++g)
                Lpart[prb + g * 16 + l16] = l_g[g];
        }
        // bounce via dead Vt buffer, per-wave region [16][136]
        bf16* eb = (bf16*)Vt + (size_t)w * 16 * 136;
#pragma unroll
        for (int g = 0; g < 2; ++g) {
            float rinv[4];
#pragma unroll
            for (int r = 0; r < 4; ++r) rinv[r] = 1.0f / __shfl(l_g[g], quad * 4 + r);
#pragma unroll
            for (int ct = 0; ct < 8; ++ct)
#pragma unroll
                for (int r = 0; r < 4; ++r)
                    eb[(quad * 4 + r) * 136 + ct * 16 + l16] =
                        (bf16)(o[g][ct][r] * rinv[r]);
            // FIX(R8): 16 rows x 128 cols = 256 x 16B chunks -> 4 passes of
            // 64 lanes (each pass: 4 rows x 16 chunks).
            int vrow = lane >> 4, vcc = lane & 15;
#pragma unroll
            for (int pass = 0; pass < 4; ++pass) {
                bf16x8 chunk = *(const bf16x8*)&eb[(pass * 4 + vrow) * 136 + vcc * 8];
                *(bf16x8*)&Opart[(prb + g * 16 + pass * 4 + vrow) * CH +
                                 cg * 128 + vcc * 8] = chunk;
            }
        }
    } else {
        float* ob = out + ((size_t)b * NPIX + n0 + qg * 32) * CH + cg * 128;
#pragma unroll
        for (int g = 0; g < 2; ++g) {
            float rinv[4];
#pragma unroll
            for (int r = 0; r < 4; ++r) rinv[r] = 1.0f / __shfl(l_g[g], quad * 4 + r);
#pragma unroll
            for (int ct = 0; ct < 8; ++ct)
#pragma unroll
                for (int r = 0; r < 4; ++r)
                    ob[(size_t)(g * 16 + quad * 4 + r) * CH + ct * 16 + l16] =
                        o[g][ct][r] * rinv[r];
        }
    }
}

// ---------------------------------------------------------------------------
// Kernel 3: merge S split-K partials: out = sum_s (l_s / sum l) * Ohat_s.
// ---------------------------------------------------------------------------
template<int S>
__global__ __launch_bounds__(256) void combine_kernel(
    const bf16* __restrict__ Opart, const float* __restrict__ Lpart,
    float* __restrict__ out)
{
    int idx  = blockIdx.x * 256 + threadIdx.x;
    int nrow = idx >> 5;
    int cc   = (idx & 31) * 8;
    int b    = nrow >> 12, nin = nrow & 4095;

    size_t pr[S];
    float  ls[S], wsum = 0.f;
#pragma unroll
    for (int s = 0; s < S; ++s) {
        pr[s] = ((size_t)s * BATCH + b) * NPIX + nin;
        ls[s] = Lpart[pr[s]];
        wsum += ls[s];
    }
    float inv = 1.0f / wsum;

    float acc[8] = {0.f, 0.f, 0.f, 0.f, 0.f, 0.f, 0.f, 0.f};
#pragma unroll
    for (int s = 0; s < S; ++s) {
        bf16x8 ov = *(const bf16x8*)&Opart[pr[s] * CH + cc];
        float wn = ls[s] * inv;
#pragma unroll
        for (int j = 0; j < 8; ++j) acc[j] += wn * (float)ov[j];
    }
    float4 o0 = {acc[0], acc[1], acc[2], acc[3]};
    float4 o1 = {acc[4], acc[5], acc[6], acc[7]};
    *(float4*)&out[(size_t)nrow * CH + cc]     = o0;
    *(float4*)&out[(size_t)nrow * CH + cc + 4] = o1;
}

extern "C" void kernel_launch(void* const* d_in, const int* in_sizes, int n_in,
                              void* d_out, int out_size, void* d_ws, size_t ws_size,
                              hipStream_t stream) {
    const float* x  = (const float*)d_in[0];
    const float* Wq = (const float*)d_in[1];
    const float* bq = (const float*)d_in[2];
    const float* Wk = (const float*)d_in[3];
    const float* bk = (const float*)d_in[4];
    const float* Wv = (const float*)d_in[5];
    const float* bv = (const float*)d_in[6];
    float* out = (float*)d_out;

    char* ws = (char*)d_ws;
    const size_t qpB   = (size_t)BATCH * NPIX * CQD * 2;   // 1 MB
    const size_t vTB   = (size_t)BATCH * CH * NPIX * 2;    // 8 MB
    const size_t WbB   = (size_t)320 * CH * 2;             // 160 KB
    const size_t bbB   = 320 * 4 + 768;                    // padded
    const size_t baseB = 2 * qpB + vTB + WbB + bbB;
    const size_t oprtB = (size_t)BATCH * NPIX * CH * 2;    // 8.4 MB per split
    const size_t mlB   = (size_t)BATCH * NPIX * 4;         // 64 KB per split

    bf16*  qp = (bf16*)ws;
    bf16*  kp = (bf16*)(ws + qpB);
    bf16*  vT = (bf16*)(ws + 2 * qpB);
    bf16*  Wb = (bf16*)(ws + 2 * qpB + vTB);
    float* bb = (float*)(ws + 2 * qpB + vTB + WbB);

    prep_kernel<<<dim3(320), dim3(256), 0, stream>>>(Wq, bq, Wk, bk, Wv, bv, Wb, bb);
    proj_kernel<<<dim3(BATCH * (NPIX / 32)), dim3(256), 0, stream>>>(
        x, Wb, bb, qp, kp, vT);

    auto need = [&](int S) { return baseB + (size_t)S * (oprtB + mlB); };
    int S = (ws_size >= need(4)) ? 4 : (ws_size >= need(2)) ? 2
          : (ws_size >= need(1)) ? 1 : 0;

    if (S > 0) {
        bf16*  Opart = (bf16*)(ws + baseB);
        float* Lpart = (float*)(ws + baseB + (size_t)S * oprtB);
        if (S == 4) {
            attn_kernel<4, false><<<dim3(256 * 4), dim3(256), 0, stream>>>(
                qp, kp, vT, Opart, Lpart, out);
            combine_kernel<4><<<dim3(2048), dim3(256), 0, stream>>>(Opart, Lpart, out);
        } else if (S == 2) {
            attn_kernel<2, false><<<dim3(256 * 2), dim3(256), 0, stream>>>(
                qp, kp, vT, Opart, Lpart, out);
            combine_kernel<2><<<dim3(2048), dim3(256), 0, stream>>>(Opart, Lpart, out);
        } else {
            attn_kernel<1, false><<<dim3(256), dim3(256), 0, stream>>>(
                qp, kp, vT, Opart, Lpart, out);
            combine_kernel<1><<<dim3(2048), dim3(256), 0, stream>>>(Opart, Lpart, out);
        }
    } else {
        attn_kernel<1, true><<<dim3(256), dim3(256), 0, stream>>>(
            qp, kp, vT, nullptr, nullptr, out);
    }
}

// Round 9
// 156.153 us; speedup vs baseline: 1.1445x; 1.1445x over previous
//
#include <hip/hip_runtime.h>

#define BATCH 4
#define CH    256
#define NPIX  4096
#define CQD   32

typedef __bf16 bf16;
typedef bf16 bf16x8 __attribute__((ext_vector_type(8)));
typedef bf16 bf16x4 __attribute__((ext_vector_type(4)));
typedef float f32x4 __attribute__((ext_vector_type(4)));

#define MFMA16 __builtin_amdgcn_mfma_f32_16x16x32_bf16

#define GLOAD_LDS16(g, l) __builtin_amdgcn_global_load_lds( \
    (const __attribute__((address_space(1))) void*)(g),     \
    (__attribute__((address_space(3))) void*)(l), 16, 0, 0)

// ---------------------------------------------------------------------------
// Kernel 0: pack weights to bf16, stacked [320][256]:
// rows 0-31 = Wq/64 (q-scale folded), 32-63 = Wk, 64-319 = Wv. Bias likewise.
// ---------------------------------------------------------------------------
__global__ __launch_bounds__(256) void prep_kernel(
    const float* __restrict__ Wq, const float* __restrict__ bq,
    const float* __restrict__ Wk, const float* __restrict__ bk,
    const float* __restrict__ Wv, const float* __restrict__ bv,
    bf16* __restrict__ Wb, float* __restrict__ bb)
{
    int r = blockIdx.x, c = threadIdx.x;
    const float* W; const float* bs; float sc; int rr;
    if (r < 32)      { W = Wq; bs = bq; sc = 0.015625f; rr = r; }
    else if (r < 64) { W = Wk; bs = bk; sc = 1.0f;      rr = r - 32; }
    else             { W = Wv; bs = bv; sc = 1.0f;      rr = r - 64; }
    Wb[(size_t)r * CH + c] = (bf16)(W[(size_t)rr * CH + c] * sc);
    if (c == 0) bb[r] = bs[rr] * sc;
}

// ---------------------------------------------------------------------------
// Kernel 1: fused 1x1-conv projections via MFMA (unchanged from R6).
// ---------------------------------------------------------------------------
__global__ __launch_bounds__(256) void proj_kernel(
    const float* __restrict__ x,
    const bf16* __restrict__ Wb, const float* __restrict__ bb,
    bf16* __restrict__ qp, bf16* __restrict__ kp, bf16* __restrict__ vT)
{
    __shared__ __align__(16) bf16 xT[32][264];       // 16.9 KB [n_local][c]
    __shared__ __align__(16) bf16 vstage[4][16][40]; // 5 KB per-wave bounce

    const int t  = threadIdx.x;
    const int b  = blockIdx.x >> 7;
    const int n0 = (blockIdx.x & 127) << 5;
    const int w    = t >> 6;
    const int lane = t & 63;
    const int l16  = t & 15;
    const int quad = (t & 63) >> 4;

    const float* xb = x + (size_t)b * CH * NPIX;
#pragma unroll
    for (int j = 0; j < 8; ++j) {
        int id = t + j * 256;
        int c  = id >> 3;
        int n4 = (id & 7) << 2;
        float4 vv = *(const float4*)(xb + (size_t)c * NPIX + n0 + n4);
        xT[n4 + 0][c] = (bf16)vv.x;
        xT[n4 + 1][c] = (bf16)vv.y;
        xT[n4 + 2][c] = (bf16)vv.z;
        xT[n4 + 3][c] = (bf16)vv.w;
    }
    __syncthreads();

    for (int rt = 0; rt < 5; ++rt) {
        int ro = w * 80 + rt * 16;
        int kind = (ro < 32) ? 0 : (ro < 64) ? 1 : 2;

        bf16x8 afrag[8];
        const bf16* wrow = Wb + (size_t)(ro + l16) * CH + quad * 8;
#pragma unroll
        for (int kc = 0; kc < 8; ++kc)
            afrag[kc] = *(const bf16x8*)(wrow + kc * 32);
        float bv4[4];
#pragma unroll
        for (int r = 0; r < 4; ++r) bv4[r] = bb[ro + quad * 4 + r];

#pragma unroll
        for (int nt = 0; nt < 2; ++nt) {
            f32x4 acc = {0.f, 0.f, 0.f, 0.f};
#pragma unroll
            for (int kc = 0; kc < 8; ++kc) {
                bf16x8 bfr = *(const bf16x8*)&xT[nt * 16 + l16][kc * 32 + quad * 8];
                acc = MFMA16(afrag[kc], bfr, acc, 0, 0, 0);
            }
            if (kind != 2) {
                bf16x4 pk;
#pragma unroll
                for (int r = 0; r < 4; ++r)
                    pk[r] = (bf16)(acc[r] + bv4[r]);
                int n = n0 + nt * 16 + l16;
                int col = (kind == 0 ? ro : ro - 32) + quad * 4;
                bf16* dst = (kind == 0) ? qp : kp;
                *(bf16x4*)&dst[((size_t)b * NPIX + n) * CQD + col] = pk;
            } else {
#pragma unroll
                for (int r = 0; r < 4; ++r)
                    vstage[w][quad * 4 + r][nt * 16 + l16] = (bf16)(acc[r] + bv4[r]);
            }
        }
        if (kind == 2) {
            int vrow = lane >> 2, vcc = lane & 3;
            bf16x8 chunk = *(const bf16x8*)&vstage[w][vrow][vcc * 8];
            *(bf16x8*)&vT[((size_t)b * CH + (ro - 64) + vrow) * NPIX + n0 + vcc * 8] = chunk;
        }
    }
}

// ---------------------------------------------------------------------------
// Kernel 2: split-K flash attention, R9: channel-split ACROSS BLOCKS with
// 64-key tiles (restores R6's conflict-free 128B-row swizzle geometry).
// Block = (b, 128 q-rows, ch-half cg, split s); 4 waves x 32 q-rows x 128 ch
// -> o = 64 AGPRs. LDS: Vt dbuf [2][128][64] 32 KB + Pb [4][2][16][64] 16 KB
// = 48 KB -> 3 blocks/CU (12 waves/CU). Async single-barrier K-loop; K-frags
// loaded per-use from global (no dbuf, saves 32 VGPRs); m=0 softmax.
// QK + Q/K loads duplicated per ch-half (cheap); only cg==0 writes Lpart.
// ---------------------------------------------------------------------------
template<int S, bool DIRECT>
__global__ __launch_bounds__(256, 3) void attn_kernel(
    const bf16* __restrict__ qp, const bf16* __restrict__ kp,
    const bf16* __restrict__ vT,
    bf16* __restrict__ Opart, float* __restrict__ Lpart,
    float* __restrict__ out)
{
    __shared__ __align__(16) bf16 Vt[2][128][64];    // 32 KB (128B rows)
    __shared__ __align__(16) bf16 Pb[4][2][16][64];  // 16 KB, wave-private

    const int t    = threadIdx.x;
    const int bid  = blockIdx.x;
    const int s    = bid % S;
    const int r2   = bid / S;
    const int cg   = r2 & 1;            // channel half (128 ch)
    const int tq   = r2 >> 1;
    const int b    = tq >> 5;
    const int qt   = tq & 31;
    const int n0   = qt << 7;           // 128 q-rows per block
    const int w    = t >> 6;            // wave = q-group of 32 rows
    const int lane = t & 63;
    const int l16  = t & 15;
    const int quad = (t & 63) >> 4;
    const int sw   = l16 & 7;           // 8-chunk swizzle key (row&7)

    const bf16* qpb = qp + ((size_t)b * NPIX + n0 + w * 32) * CQD;
    bf16x8 qfrag[2];
    qfrag[0] = *(const bf16x8*)(qpb + (size_t)l16 * CQD + quad * 8);
    qfrag[1] = *(const bf16x8*)(qpb + (size_t)(16 + l16) * CQD + quad * 8);

    f32x4 o[2][8];
#pragma unroll
    for (int g = 0; g < 2; ++g)
#pragma unroll
        for (int ct = 0; ct < 8; ++ct) o[g][ct] = (f32x4){0.f, 0.f, 0.f, 0.f};
    float lsum[2] = {0.f, 0.f};

    const bf16* kpb = kp + (size_t)b * NPIX * CQD;
    const bf16* vTb = vT + ((size_t)b * CH + cg * 128) * NPIX;
    const int k0 = s * (NPIX / S);
    const int iters = NPIX / S / 64;

    // Vt staging: 128 rows x 64 keys (128 B = 8 chunks/row). Per wave 4 calls
    // x (8 rows x 128 B). LDS slot sC of row r holds global chunk sC^(r&7).
    const int vrow_off = lane >> 3;
    const int vchunk   = (lane & 7) ^ vrow_off;
    auto issue_vt = [&](int buf, int m0) {
#pragma unroll
        for (int j = 0; j < 4; ++j) {
            int rowbase = w * 32 + j * 8;
            const bf16* src = vTb + (size_t)(rowbase + vrow_off) * NPIX + m0 + vchunk * 8;
            GLOAD_LDS16(src, &Vt[buf][rowbase][0]);
        }
    };

    issue_vt(0, k0);
    __syncthreads();   // drains prologue Vt

    for (int mi = 0; mi < iters; ++mi) {
        const int cur = mi & 1;
        const int m0  = k0 + (mi << 6);
        if (mi + 1 < iters)            // prefetch next Vt tile (hidden by compute)
            issue_vt(cur ^ 1, m0 + 64);

        // K-frags per-use from global (L2-warm; hidden by 3-blocks/CU TLP)
        bf16x8 kf[4];
#pragma unroll
        for (int mt = 0; mt < 4; ++mt)
            kf[mt] = *(const bf16x8*)(kpb + (size_t)(m0 + mt * 16 + l16) * CQD + quad * 8);

        // S^T = K Q^T : D[key=mt*16+quad*4+r][q=l16]
        f32x4 sv[2][4];
#pragma unroll
        for (int mt = 0; mt < 4; ++mt) {
            f32x4 z = {0.f, 0.f, 0.f, 0.f};
            sv[0][mt] = MFMA16(kf[mt], qfrag[0], z, 0, 0, 0);
            sv[1][mt] = MFMA16(kf[mt], qfrag[1], z, 0, 0, 0);
        }

        // p = exp(s) (m=0); dual Pb; 8B chunk (2mt+(quad>>1)) stored at ^sw
#pragma unroll
        for (int g = 0; g < 2; ++g) {
            float rs = 0.f;
#pragma unroll
            for (int mt = 0; mt < 4; ++mt) {
                bf16x4 pk;
#pragma unroll
                for (int r = 0; r < 4; ++r) {
                    float e = __expf(sv[g][mt][r]);
                    rs += e;
                    pk[r] = (bf16)e;
                }
                int slot = (2 * mt + (quad >> 1)) ^ sw;
                *(bf16x4*)&Pb[w][g][l16][slot * 8 + (quad & 1) * 4] = pk;
            }
            lsum[g] += rs;
        }
        bf16x8 pf[2][2];
#pragma unroll
        for (int g = 0; g < 2; ++g)
#pragma unroll
            for (int kc = 0; kc < 2; ++kc) {
                int slot = (4 * kc + quad) ^ sw;
                pf[g][kc] = *(const bf16x8*)&Pb[w][g][l16][slot * 8];
            }

        // PV over this block's 128-ch half; Vt row&7 == sw
#pragma unroll
        for (int ct = 0; ct < 8; ++ct) {
            int row = ct * 16 + l16;
            bf16x8 v0 = *(const bf16x8*)&Vt[cur][row][((quad) ^ sw) * 8];
            bf16x8 v1 = *(const bf16x8*)&Vt[cur][row][((4 + quad) ^ sw) * 8];
            o[0][ct] = MFMA16(pf[0][0], v0, o[0][ct], 0, 0, 0);
            o[0][ct] = MFMA16(pf[0][1], v1, o[0][ct], 0, 0, 0);
            o[1][ct] = MFMA16(pf[1][0], v0, o[1][ct], 0, 0, 0);
            o[1][ct] = MFMA16(pf[1][1], v1, o[1][ct], 0, 0, 0);
        }
        __syncthreads();   // single barrier: drains prefetch vmcnt + buffer swap
    }

    float l_g[2];
#pragma unroll
    for (int g = 0; g < 2; ++g) {
        float v = lsum[g];
        v += __shfl_xor(v, 16);
        v += __shfl_xor(v, 32);
        l_g[g] = v;
    }

    if (!DIRECT) {
        const size_t prb = ((size_t)s * BATCH + b) * NPIX + n0 + w * 32;
        if (cg == 0 && quad == 0) {
#pragma unroll
            for (int g = 0; g < 2; ++g)
                Lpart[prb + g * 16 + l16] = l_g[g];
        }
        // bounce via dead Vt buffer, per-wave region [16][136] (wave-private)
        bf16* eb = (bf16*)Vt + (size_t)w * 16 * 136;
#pragma unroll
        for (int g = 0; g < 2; ++g) {
            float rinv[4];
#pragma unroll
            for (int r = 0; r < 4; ++r) rinv[r] = 1.0f / __shfl(l_g[g], quad * 4 + r);
#pragma unroll
            for (int ct = 0; ct < 8; ++ct)
#pragma unroll
                for (int r = 0; r < 4; ++r)
                    eb[(quad * 4 + r) * 136 + ct * 16 + l16] =
                        (bf16)(o[g][ct][r] * rinv[r]);
            // 16 rows x 128 cols = 256 x 16B chunks -> 4 passes of 64 lanes
            int vrow = lane >> 4, vcc = lane & 15;
#pragma unroll
            for (int pass = 0; pass < 4; ++pass) {
                bf16x8 chunk = *(const bf16x8*)&eb[(pass * 4 + vrow) * 136 + vcc * 8];
                *(bf16x8*)&Opart[(prb + g * 16 + pass * 4 + vrow) * CH +
                                 cg * 128 + vcc * 8] = chunk;
            }
        }
    } else {
        float* ob = out + ((size_t)b * NPIX + n0 + w * 32) * CH + cg * 128;
#pragma unroll
        for (int g = 0; g < 2; ++g) {
            float rinv[4];
#pragma unroll
            for (int r = 0; r < 4; ++r) rinv[r] = 1.0f / __shfl(l_g[g], quad * 4 + r);
#pragma unroll
            for (int ct = 0; ct < 8; ++ct)
#pragma unroll
                for (int r = 0; r < 4; ++r)
                    ob[(size_t)(g * 16 + quad * 4 + r) * CH + ct * 16 + l16] =
                        o[g][ct][r] * rinv[r];
        }
    }
}

// ---------------------------------------------------------------------------
// Kernel 3: merge S split-K partials: out = sum_s (l_s / sum l) * Ohat_s.
// ---------------------------------------------------------------------------
template<int S>
__global__ __launch_bounds__(256) void combine_kernel(
    const bf16* __restrict__ Opart, const float* __restrict__ Lpart,
    float* __restrict__ out)
{
    int idx  = blockIdx.x * 256 + threadIdx.x;
    int nrow = idx >> 5;
    int cc   = (idx & 31) * 8;
    int b    = nrow >> 12, nin = nrow & 4095;

    size_t pr[S];
    float  ls[S], wsum = 0.f;
#pragma unroll
    for (int s = 0; s < S; ++s) {
        pr[s] = ((size_t)s * BATCH + b) * NPIX + nin;
        ls[s] = Lpart[pr[s]];
        wsum += ls[s];
    }
    float inv = 1.0f / wsum;

    float acc[8] = {0.f, 0.f, 0.f, 0.f, 0.f, 0.f, 0.f, 0.f};
#pragma unroll
    for (int s = 0; s < S; ++s) {
        bf16x8 ov = *(const bf16x8*)&Opart[pr[s] * CH + cc];
        float wn = ls[s] * inv;
#pragma unroll
        for (int j = 0; j < 8; ++j) acc[j] += wn * (float)ov[j];
    }
    float4 o0 = {acc[0], acc[1], acc[2], acc[3]};
    float4 o1 = {acc[4], acc[5], acc[6], acc[7]};
    *(float4*)&out[(size_t)nrow * CH + cc]     = o0;
    *(float4*)&out[(size_t)nrow * CH + cc + 4] = o1;
}

extern "C" void kernel_launch(void* const* d_in, const int* in_sizes, int n_in,
                              void* d_out, int out_size, void* d_ws, size_t ws_size,
                              hipStream_t stream) {
    const float* x  = (const float*)d_in[0];
    const float* Wq = (const float*)d_in[1];
    const float* bq = (const float*)d_in[2];
    const float* Wk = (const float*)d_in[3];
    const float* bk = (const float*)d_in[4];
    const float* Wv = (const float*)d_in[5];
    const float* bv = (const float*)d_in[6];
    float* out = (float*)d_out;

    char* ws = (char*)d_ws;
    const size_t qpB   = (size_t)BATCH * NPIX * CQD * 2;   // 1 MB
    const size_t vTB   = (size_t)BATCH * CH * NPIX * 2;    // 8 MB
    const size_t WbB   = (size_t)320 * CH * 2;             // 160 KB
    const size_t bbB   = 320 * 4 + 768;                    // padded
    const size_t baseB = 2 * qpB + vTB + WbB + bbB;
    const size_t oprtB = (size_t)BATCH * NPIX * CH * 2;    // 8.4 MB per split
    const size_t mlB   = (size_t)BATCH * NPIX * 4;         // 64 KB per split

    bf16*  qp = (bf16*)ws;
    bf16*  kp = (bf16*)(ws + qpB);
    bf16*  vT = (bf16*)(ws + 2 * qpB);
    bf16*  Wb = (bf16*)(ws + 2 * qpB + vTB);
    float* bb = (float*)(ws + 2 * qpB + vTB + WbB);

    prep_kernel<<<dim3(320), dim3(256), 0, stream>>>(Wq, bq, Wk, bk, Wv, bv, Wb, bb);
    proj_kernel<<<dim3(BATCH * (NPIX / 32)), dim3(256), 0, stream>>>(
        x, Wb, bb, qp, kp, vT);

    auto need = [&](int S) { return baseB + (size_t)S * (oprtB + mlB); };
    int S = (ws_size >= need(4)) ? 4 : (ws_size >= need(2)) ? 2
          : (ws_size >= need(1)) ? 1 : 0;

    // grid per split: BATCH * 32 q-tiles * 2 ch-halves = 256 blocks
    if (S > 0) {
        bf16*  Opart = (bf16*)(ws + baseB);
        float* Lpart = (float*)(ws + baseB + (size_t)S * oprtB);
        if (S == 4) {
            attn_kernel<4, false><<<dim3(256 * 4), dim3(256), 0, stream>>>(
                qp, kp, vT, Opart, Lpart, out);
            combine_kernel<4><<<dim3(2048), dim3(256), 0, stream>>>(Opart, Lpart, out);
        } else if (S == 2) {
            attn_kernel<2, false><<<dim3(256 * 2), dim3(256), 0, stream>>>(
                qp, kp, vT, Opart, Lpart, out);
            combine_kernel<2><<<dim3(2048), dim3(256), 0, stream>>>(Opart, Lpart, out);
        } else {
            attn_kernel<1, false><<<dim3(256), dim3(256), 0, stream>>>(
                qp, kp, vT, Opart, Lpart, out);
            combine_kernel<1><<<dim3(2048), dim3(256), 0, stream>>>(Opart, Lpart, out);
        }
    } else {
        attn_kernel<1, true><<<dim3(256), dim3(256), 0, stream>>>(
            qp, kp, vT, nullptr, nullptr, out);
    }
}

// Round 10
// 140.938 us; speedup vs baseline: 1.2681x; 1.1080x over previous
//
#include <hip/hip_runtime.h>

#define BATCH 4
#define CH    256
#define NPIX  4096
#define CQD   32

typedef __bf16 bf16;
typedef bf16 bf16x8 __attribute__((ext_vector_type(8)));
typedef bf16 bf16x4 __attribute__((ext_vector_type(4)));
typedef float f32x4 __attribute__((ext_vector_type(4)));
typedef float f32x16 __attribute__((ext_vector_type(16)));

#define MFMA16 __builtin_amdgcn_mfma_f32_16x16x32_bf16
#define MFMA32 __builtin_amdgcn_mfma_f32_32x32x16_bf16

#define GLOAD_LDS16(g, l) __builtin_amdgcn_global_load_lds( \
    (const __attribute__((address_space(1))) void*)(g),     \
    (__attribute__((address_space(3))) void*)(l), 16, 0, 0)

// ---------------------------------------------------------------------------
// Kernel 0: pack weights to bf16, stacked [320][256] (q-scale folded).
// ---------------------------------------------------------------------------
__global__ __launch_bounds__(256) void prep_kernel(
    const float* __restrict__ Wq, const float* __restrict__ bq,
    const float* __restrict__ Wk, const float* __restrict__ bk,
    const float* __restrict__ Wv, const float* __restrict__ bv,
    bf16* __restrict__ Wb, float* __restrict__ bb)
{
    int r = blockIdx.x, c = threadIdx.x;
    const float* W; const float* bs; float sc; int rr;
    if (r < 32)      { W = Wq; bs = bq; sc = 0.015625f; rr = r; }
    else if (r < 64) { W = Wk; bs = bk; sc = 1.0f;      rr = r - 32; }
    else             { W = Wv; bs = bv; sc = 1.0f;      rr = r - 64; }
    Wb[(size_t)r * CH + c] = (bf16)(W[(size_t)rr * CH + c] * sc);
    if (c == 0) bb[r] = bs[rr] * sc;
}

// ---------------------------------------------------------------------------
// Kernel 1: fused 1x1-conv projections via MFMA (unchanged from R6).
// ---------------------------------------------------------------------------
__global__ __launch_bounds__(256) void proj_kernel(
    const float* __restrict__ x,
    const bf16* __restrict__ Wb, const float* __restrict__ bb,
    bf16* __restrict__ qp, bf16* __restrict__ kp, bf16* __restrict__ vT)
{
    __shared__ __align__(16) bf16 xT[32][264];
    __shared__ __align__(16) bf16 vstage[4][16][40];

    const int t  = threadIdx.x;
    const int b  = blockIdx.x >> 7;
    const int n0 = (blockIdx.x & 127) << 5;
    const int w    = t >> 6;
    const int lane = t & 63;
    const int l16  = t & 15;
    const int quad = (t & 63) >> 4;

    const float* xb = x + (size_t)b * CH * NPIX;
#pragma unroll
    for (int j = 0; j < 8; ++j) {
        int id = t + j * 256;
        int c  = id >> 3;
        int n4 = (id & 7) << 2;
        float4 vv = *(const float4*)(xb + (size_t)c * NPIX + n0 + n4);
        xT[n4 + 0][c] = (bf16)vv.x;
        xT[n4 + 1][c] = (bf16)vv.y;
        xT[n4 + 2][c] = (bf16)vv.z;
        xT[n4 + 3][c] = (bf16)vv.w;
    }
    __syncthreads();

    for (int rt = 0; rt < 5; ++rt) {
        int ro = w * 80 + rt * 16;
        int kind = (ro < 32) ? 0 : (ro < 64) ? 1 : 2;

        bf16x8 afrag[8];
        const bf16* wrow = Wb + (size_t)(ro + l16) * CH + quad * 8;
#pragma unroll
        for (int kc = 0; kc < 8; ++kc)
            afrag[kc] = *(const bf16x8*)(wrow + kc * 32);
        float bv4[4];
#pragma unroll
        for (int r = 0; r < 4; ++r) bv4[r] = bb[ro + quad * 4 + r];

#pragma unroll
        for (int nt = 0; nt < 2; ++nt) {
            f32x4 acc = {0.f, 0.f, 0.f, 0.f};
#pragma unroll
            for (int kc = 0; kc < 8; ++kc) {
                bf16x8 bfr = *(const bf16x8*)&xT[nt * 16 + l16][kc * 32 + quad * 8];
                acc = MFMA16(afrag[kc], bfr, acc, 0, 0, 0);
            }
            if (kind != 2) {
                bf16x4 pk;
#pragma unroll
                for (int r = 0; r < 4; ++r)
                    pk[r] = (bf16)(acc[r] + bv4[r]);
                int n = n0 + nt * 16 + l16;
                int col = (kind == 0 ? ro : ro - 32) + quad * 4;
                bf16* dst = (kind == 0) ? qp : kp;
                *(bf16x4*)&dst[((size_t)b * NPIX + n) * CQD + col] = pk;
            } else {
#pragma unroll
                for (int r = 0; r < 4; ++r)
                    vstage[w][quad * 4 + r][nt * 16 + l16] = (bf16)(acc[r] + bv4[r]);
            }
        }
        if (kind == 2) {
            int vrow = lane >> 2, vcc = lane & 3;
            bf16x8 chunk = *(const bf16x8*)&vstage[w][vrow][vcc * 8];
            *(bf16x8*)&vT[((size_t)b * CH + (ro - 64) + vrow) * NPIX + n0 + vcc * 8] = chunk;
        }
    }
}

// ---------------------------------------------------------------------------
// Kernel 2: split-K flash attention, R10: 32x32x16 PV + block-shared P.
// Block = 128 q x 256 ch (as R6). Softmax: wave w computes S^T/exp for
// q-rows w*32..+31 (NO duplication) -> shared PbS[128][64]. PV: wave =
// (qh = w>>1: 64 q) x (chb = (w&1)*128 ch) via 8 tiles of 32x32 (128 AGPR).
// 32x32 B-frag covers 32 ch/16 keys -> Vt read bytes per block-iter halve
// (128->64 KB). 2 barriers/iter (PbS cross-wave). Vt dbuf + global_load_lds
// prefetch and reg K-dbuf retained from R6. m=0 softmax.
// ---------------------------------------------------------------------------
template<int S, bool DIRECT>
__global__ __launch_bounds__(256, 2) void attn_kernel(
    const bf16* __restrict__ qp, const bf16* __restrict__ kp,
    const bf16* __restrict__ vT,
    bf16* __restrict__ Opart, float* __restrict__ Lpart,
    float* __restrict__ out)
{
    __shared__ __align__(16) bf16 Vt[2][256][64];   // 64 KB
    __shared__ __align__(16) bf16 PbS[128][64];     // 16 KB, block-shared

    const int t    = threadIdx.x;
    const int bid  = blockIdx.x;
    const int s    = bid % S;
    const int tq   = bid / S;
    const int b    = tq >> 5;
    const int qt   = tq & 31;
    const int n0   = qt << 7;
    const int w    = t >> 6;
    const int lane = t & 63;
    const int l16  = t & 15;
    const int quad = (t & 63) >> 4;
    const int sw   = l16 & 7;
    const int l32  = lane & 31;
    const int h    = lane >> 5;
    const int qh   = w >> 1;            // PV q-half (64 rows)
    const int chb  = (w & 1) * 128;     // PV channel half

    const bf16* qpb = qp + ((size_t)b * NPIX + n0 + w * 32) * CQD;
    bf16x8 qfrag[2];
    qfrag[0] = *(const bf16x8*)(qpb + (size_t)l16 * CQD + quad * 8);
    qfrag[1] = *(const bf16x8*)(qpb + (size_t)(16 + l16) * CQD + quad * 8);

    f32x16 o[2][4];   // [t32 q-tile][ct ch-tile], D[m=q][n=ch]
#pragma unroll
    for (int i = 0; i < 2; ++i)
#pragma unroll
        for (int j = 0; j < 4; ++j)
#pragma unroll
            for (int r = 0; r < 16; ++r) o[i][j][r] = 0.f;
    float lsum[2] = {0.f, 0.f};

    const bf16* kpb = kp + (size_t)b * NPIX * CQD;
    const bf16* vTb = vT + (size_t)b * CH * NPIX;
    const int k0 = s * (NPIX / S);
    const int iters = NPIX / S / 64;

    const int vrow_off = lane >> 3;
    const int vchunk   = (lane & 7) ^ vrow_off;
    auto issue_vt = [&](int buf, int m0) {
#pragma unroll
        for (int j = 0; j < 8; ++j) {
            int rowbase = j * 32 + w * 8;
            const bf16* src = vTb + (size_t)(rowbase + vrow_off) * NPIX + m0 + vchunk * 8;
            GLOAD_LDS16(src, &Vt[buf][rowbase][0]);
        }
    };
    auto load_kf = [&](int m0, bf16x8* kf) {
#pragma unroll
        for (int mt = 0; mt < 4; ++mt)
            kf[mt] = *(const bf16x8*)(kpb + (size_t)(m0 + mt * 16 + l16) * CQD + quad * 8);
    };

    bf16x8 kfa[4], kfb[4];
    issue_vt(0, k0);
    load_kf(k0, kfa);
    __syncthreads();

    for (int mi = 0; mi < iters; ++mi) {
        const int cur = mi & 1;
        const int m0  = k0 + (mi << 6);
        if (mi + 1 < iters) {
            issue_vt(cur ^ 1, m0 + 64);
            load_kf(m0 + 64, kfb);
        }

        // S^T tiles for this wave's 32 q: D[key=mt*16+quad*4+r][q=w*32+g*16+l16]
        f32x4 sv[2][4];
#pragma unroll
        for (int mt = 0; mt < 4; ++mt) {
            f32x4 z = {0.f, 0.f, 0.f, 0.f};
            sv[0][mt] = MFMA16(kfa[mt], qfrag[0], z, 0, 0, 0);
            sv[1][mt] = MFMA16(kfa[mt], qfrag[1], z, 0, 0, 0);
        }

        // p = exp(s) (m=0) -> shared PbS[q][key], 16B chunk c at slot c^(q&7)
#pragma unroll
        for (int g = 0; g < 2; ++g) {
            float rs = 0.f;
#pragma unroll
            for (int mt = 0; mt < 4; ++mt) {
                bf16x4 pk;
#pragma unroll
                for (int r = 0; r < 4; ++r) {
                    float e = __expf(sv[g][mt][r]);
                    rs += e;
                    pk[r] = (bf16)e;
                }
                int slot = (2 * mt + (quad >> 1)) ^ sw;
                *(bf16x4*)&PbS[w * 32 + g * 16 + l16][slot * 8 + (quad & 1) * 4] = pk;
            }
            lsum[g] += rs;
        }
        __syncthreads();   // PbS visible to all waves (also drains prefetch)

        // PV: A = P[32q x 16k] frags from PbS, B = V[16k x 32ch] from Vt.
        // A/B lane: row/col = lane&31, k = (lane>>5)*8 + j.
        bf16x8 pA[2][4];
#pragma unroll
        for (int t32 = 0; t32 < 2; ++t32)
#pragma unroll
            for (int kg = 0; kg < 4; ++kg) {
                int row = qh * 64 + t32 * 32 + l32;
                pA[t32][kg] = *(const bf16x8*)&PbS[row][((2 * kg + h) ^ (l32 & 7)) * 8];
            }
#pragma unroll
        for (int ct = 0; ct < 4; ++ct) {
            int vrow = chb + ct * 32 + l32;
            bf16x8 vB[4];
#pragma unroll
            for (int kg = 0; kg < 4; ++kg)
                vB[kg] = *(const bf16x8*)&Vt[cur][vrow][((2 * kg + h) ^ (l32 & 7)) * 8];
#pragma unroll
            for (int t32 = 0; t32 < 2; ++t32)
#pragma unroll
                for (int kg = 0; kg < 4; ++kg)
                    o[t32][ct] = MFMA32(pA[t32][kg], vB[kg], o[t32][ct], 0, 0, 0);
        }
        __syncthreads();   // PbS/Vt consumed before next iter's writes/staging
#pragma unroll
        for (int i = 0; i < 4; ++i) kfa[i] = kfb[i];
    }

    // final l: reduce quad partials; rows w*32+g*16+l16
    float l_g[2];
#pragma unroll
    for (int g = 0; g < 2; ++g) {
        float v = lsum[g];
        v += __shfl_xor(v, 16);
        v += __shfl_xor(v, 32);
        l_g[g] = v;
    }
    float* lsh = (float*)PbS;          // PbS dead after final barrier
    if (quad == 0) {
#pragma unroll
        for (int g = 0; g < 2; ++g)
            lsh[w * 32 + g * 16 + l16] = l_g[g];
    }
    __syncthreads();

    const size_t prb2 = ((size_t)s * BATCH + b) * NPIX + n0;
    if (!DIRECT && quad == 0) {
#pragma unroll
        for (int g = 0; g < 2; ++g)
            Lpart[prb2 + w * 32 + g * 16 + l16] = l_g[g];
    }

    // epilogue: D layout row(q) = (reg&3)+8*(reg>>2)+4*h, col(ch) = l32.
    bf16* eb = (bf16*)Vt + (size_t)w * 32 * 136;   // wave-private bounce
#pragma unroll
    for (int t32 = 0; t32 < 2; ++t32) {
        float rinv[16];
#pragma unroll
        for (int reg = 0; reg < 16; ++reg) {
            int q_r = (reg & 3) + 8 * (reg >> 2) + 4 * h;
            rinv[reg] = 1.0f / lsh[qh * 64 + t32 * 32 + q_r];
        }
        if (!DIRECT) {
#pragma unroll
            for (int ct = 0; ct < 4; ++ct)
#pragma unroll
                for (int reg = 0; reg < 16; ++reg) {
                    int q_r = (reg & 3) + 8 * (reg >> 2) + 4 * h;
                    eb[q_r * 136 + ct * 32 + l32] = (bf16)(o[t32][ct][reg] * rinv[reg]);
                }
            // 32 rows x 128 ch = 8192 B = 64 lanes x 16B x 8 passes
            int vrow = lane >> 4, vcc = lane & 15;
#pragma unroll
            for (int p = 0; p < 8; ++p) {
                int row = p * 4 + vrow;
                bf16x8 chunk = *(const bf16x8*)&eb[row * 136 + vcc * 8];
                *(bf16x8*)&Opart[(prb2 + qh * 64 + t32 * 32 + row) * CH +
                                 chb + vcc * 8] = chunk;
            }
        } else {
            float* ob = out + (prb2 + qh * 64 + t32 * 32) * CH + chb;
#pragma unroll
            for (int ct = 0; ct < 4; ++ct)
#pragma unroll
                for (int reg = 0; reg < 16; ++reg) {
                    int q_r = (reg & 3) + 8 * (reg >> 2) + 4 * h;
                    ob[(size_t)q_r * CH + ct * 32 + l32] = o[t32][ct][reg] * rinv[reg];
                }
        }
    }
}

// ---------------------------------------------------------------------------
// Kernel 3: merge S split-K partials: out = sum_s (l_s / sum l) * Ohat_s.
// ---------------------------------------------------------------------------
template<int S>
__global__ __launch_bounds__(256) void combine_kernel(
    const bf16* __restrict__ Opart, const float* __restrict__ Lpart,
    float* __restrict__ out)
{
    int idx  = blockIdx.x * 256 + threadIdx.x;
    int nrow = idx >> 5;
    int cc   = (idx & 31) * 8;
    int b    = nrow >> 12, nin = nrow & 4095;

    size_t pr[S];
    float  ls[S], wsum = 0.f;
#pragma unroll
    for (int s = 0; s < S; ++s) {
        pr[s] = ((size_t)s * BATCH + b) * NPIX + nin;
        ls[s] = Lpart[pr[s]];
        wsum += ls[s];
    }
    float inv = 1.0f / wsum;

    float acc[8] = {0.f, 0.f, 0.f, 0.f, 0.f, 0.f, 0.f, 0.f};
#pragma unroll
    for (int s = 0; s < S; ++s) {
        bf16x8 ov = *(const bf16x8*)&Opart[pr[s] * CH + cc];
        float wn = ls[s] * inv;
#pragma unroll
        for (int j = 0; j < 8; ++j) acc[j] += wn * (float)ov[j];
    }
    float4 o0 = {acc[0], acc[1], acc[2], acc[3]};
    float4 o1 = {acc[4], acc[5], acc[6], acc[7]};
    *(float4*)&out[(size_t)nrow * CH + cc]     = o0;
    *(float4*)&out[(size_t)nrow * CH + cc + 4] = o1;
}

extern "C" void kernel_launch(void* const* d_in, const int* in_sizes, int n_in,
                              void* d_out, int out_size, void* d_ws, size_t ws_size,
                              hipStream_t stream) {
    const float* x  = (const float*)d_in[0];
    const float* Wq = (const float*)d_in[1];
    const float* bq = (const float*)d_in[2];
    const float* Wk = (const float*)d_in[3];
    const float* bk = (const float*)d_in[4];
    const float* Wv = (const float*)d_in[5];
    const float* bv = (const float*)d_in[6];
    float* out = (float*)d_out;

    char* ws = (char*)d_ws;
    const size_t qpB   = (size_t)BATCH * NPIX * CQD * 2;   // 1 MB
    const size_t vTB   = (size_t)BATCH * CH * NPIX * 2;    // 8 MB
    const size_t WbB   = (size_t)320 * CH * 2;             // 160 KB
    const size_t bbB   = 320 * 4 + 768;                    // padded
    const size_t baseB = 2 * qpB + vTB + WbB + bbB;
    const size_t oprtB = (size_t)BATCH * NPIX * CH * 2;    // 8.4 MB per split
    const size_t mlB   = (size_t)BATCH * NPIX * 4;         // 64 KB per split

    bf16*  qp = (bf16*)ws;
    bf16*  kp = (bf16*)(ws + qpB);
    bf16*  vT = (bf16*)(ws + 2 * qpB);
    bf16*  Wb = (bf16*)(ws + 2 * qpB + vTB);
    float* bb = (float*)(ws + 2 * qpB + vTB + WbB);

    prep_kernel<<<dim3(320), dim3(256), 0, stream>>>(Wq, bq, Wk, bk, Wv, bv, Wb, bb);
    proj_kernel<<<dim3(BATCH * (NPIX / 32)), dim3(256), 0, stream>>>(
        x, Wb, bb, qp, kp, vT);

    auto need = [&](int S) { return baseB + (size_t)S * (oprtB + mlB); };
    int S = (ws_size >= need(4)) ? 4 : (ws_size >= need(2)) ? 2
          : (ws_size >= need(1)) ? 1 : 0;

    if (S > 0) {
        bf16*  Opart = (bf16*)(ws + baseB);
        float* Lpart = (float*)(ws + baseB + (size_t)S * oprtB);
        if (S == 4) {
            attn_kernel<4, false><<<dim3(128 * 4), dim3(256), 0, stream>>>(
                qp, kp, vT, Opart, Lpart, out);
            combine_kernel<4><<<dim3(2048), dim3(256), 0, stream>>>(Opart, Lpart, out);
        } else if (S == 2) {
            attn_kernel<2, false><<<dim3(128 * 2), dim3(256), 0, stream>>>(
                qp, kp, vT, Opart, Lpart, out);
            combine_kernel<2><<<dim3(2048), dim3(256), 0, stream>>>(Opart, Lpart, out);
        } else {
            attn_kernel<1, false><<<dim3(128), dim3(256), 0, stream>>>(
                qp, kp, vT, Opart, Lpart, out);
            combine_kernel<1><<<dim3(2048), dim3(256), 0, stream>>>(Opart, Lpart, out);
        }
    } else {
        attn_kernel<1, true><<<dim3(128), dim3(256), 0, stream>>>(
            qp, kp, vT, nullptr, nullptr, out);
    }
}